// Round 8
// baseline (338.626 us; speedup 1.0000x reference)
//
#include <hip/hip_runtime.h>
#include <stdint.h>
#include <math.h>

#define Bn 64
#define Tn 512
#define Dn 1024
#define Ln 32
#define LOG2E 1.4426950408889634f
#define LN2f  0.6931471805599453f

// workspace float offsets
#define EMIS_OFF 0
#define LOGNORM_OFF (Bn * Tn * Ln)
#define SCORE_OFF (LOGNORM_OFF + Bn)
#define CNT_OFF (SCORE_OFF + Bn)

// max3 helper: compiler fuses fmaxf(fmaxf(a,b),c) -> v_max3_f32
#define MAX3(a,b,c) fmaxf(fmaxf((a),(b)),(c))

// DPP row rotate (16-lane row), K = compile-time rotate amount.
template<int K>
__device__ __forceinline__ float rorf(float v) {
    return __int_as_float(__builtin_amdgcn_update_dpp(
        0, __float_as_int(v), 0x120 | K, 0xF, 0xF, true));
}

// Opaque register copy: compiler cannot prove r == v, so the two swap
// operands land in distinct physical registers (R3 bugfix, R4-verified).
__device__ __forceinline__ float opaque_copy(float v) {
    float r;
    asm("v_mov_b32 %0, %1" : "=v"(r) : "v"(v));
    return r;
}

// cross-lane swaps; after the op {x,y} hold {own, other} in some order on
// every lane, so a commutative combine needs no polarity select.
__device__ __forceinline__ void swap32p(float p, float& x, float& y) {
    x = p;
    y = opaque_copy(p);
    asm("v_permlane32_swap_b32 %0, %1" : "+v"(x), "+v"(y));
}
__device__ __forceinline__ void swap16p(float p, float& x, float& y) {
    x = p;
    y = opaque_copy(p);
    asm("v_permlane16_swap_b32 %0, %1" : "+v"(x), "+v"(y));
}

// ---------------------------------------------------------------------------
// Kernel 1: emissions = x @ W + bias. 256 blocks x 128 threads.
// R8: 8x4 thread tile. Per k: 3 ds_read_b128 feed 32 fma (was 2 reads/16 fma
// at 4 waves -> 96 cyc/k LDS). Now 2 waves x 3 reads = 72 cyc/k. LDS-bound
// kernel => fewer waves with better fma:read ratio wins; idle SIMDs are free.
// Bank check: 8 row-octet addresses/wave span 64 floats -> 2-way (free).
// ---------------------------------------------------------------------------
#define BM 128
#define KB 32
#define XSS 132

__global__ __launch_bounds__(128) void gemm_emis(
    const float* __restrict__ x, const float* __restrict__ Wm,
    const float* __restrict__ bias, const int* __restrict__ seqlen,
    float* __restrict__ emis)
{
    int b  = blockIdx.x >> 2;
    int t0 = (blockIdx.x & 3) * BM;
    if (t0 >= seqlen[b]) return;

    __shared__ __align__(16) float xs[KB * XSS];   // transposed: xs[k][row]
    __shared__ __align__(16) float wsh[KB * Ln];   // wsh[k][col]

    int tid = threadIdx.x;
    int cg = tid & 7;       // cols 4cg..4cg+3
    int rg = tid >> 3;      // rows 8rg..8rg+7 (0..15)

    const float* xrow = x + (size_t)(b * Tn + t0) * Dn;

    float acc[8][4];
    #pragma unroll
    for (int z = 0; z < 8; z++)
        #pragma unroll
        for (int c = 0; c < 4; c++) acc[z][c] = 0.f;

    // prologue: prefetch chunk 0 into registers
    float4 xr[8]; float4 wr[2];
    #pragma unroll
    for (int u = 0; u < 8; u++) {
        int f = tid + 128 * u;
        xr[u] = *(const float4*)(xrow + (size_t)(f >> 3) * Dn + (f & 7) * 4);
    }
    wr[0] = *(const float4*)(Wm + tid * 4);
    wr[1] = *(const float4*)(Wm + (tid + 128) * 4);

    for (int k0 = 0; k0 < Dn; k0 += KB) {
        __syncthreads();
        #pragma unroll
        for (int u = 0; u < 8; u++) {
            int f = tid + 128 * u;
            int lrow = f >> 3, kk = f & 7;
            xs[(4 * kk + 0) * XSS + lrow] = xr[u].x;
            xs[(4 * kk + 1) * XSS + lrow] = xr[u].y;
            xs[(4 * kk + 2) * XSS + lrow] = xr[u].z;
            xs[(4 * kk + 3) * XSS + lrow] = xr[u].w;
        }
        *(float4*)(wsh + tid * 4) = wr[0];
        *(float4*)(wsh + (tid + 128) * 4) = wr[1];
        __syncthreads();

        int kn = k0 + KB;
        if (kn < Dn) {
            #pragma unroll
            for (int u = 0; u < 8; u++) {
                int f = tid + 128 * u;
                xr[u] = *(const float4*)(xrow + (size_t)(f >> 3) * Dn + kn + (f & 7) * 4);
            }
            wr[0] = *(const float4*)(Wm + (size_t)kn * Ln + tid * 4);
            wr[1] = *(const float4*)(Wm + (size_t)kn * Ln + (tid + 128) * 4);
        }

        #pragma unroll 8
        for (int k = 0; k < KB; k++) {
            float4 a0 = *(const float4*)(xs + k * XSS + 8 * rg);
            float4 a1 = *(const float4*)(xs + k * XSS + 8 * rg + 4);
            float4 w = *(const float4*)(wsh + k * Ln + 4 * cg);
            float av[8] = {a0.x, a0.y, a0.z, a0.w, a1.x, a1.y, a1.z, a1.w};
            float wv[4] = {w.x, w.y, w.z, w.w};
            #pragma unroll
            for (int z = 0; z < 8; z++)
                #pragma unroll
                for (int c = 0; c < 4; c++)
                    acc[z][c] = fmaf(av[z], wv[c], acc[z][c]);
        }
    }

    float4 bv = *(const float4*)(bias + 4 * cg);
    float bb[4] = {bv.x, bv.y, bv.z, bv.w};
    #pragma unroll
    for (int z = 0; z < 8; z++) {
        float4 o;
        o.x = acc[z][0] + bb[0];
        o.y = acc[z][1] + bb[1];
        o.z = acc[z][2] + bb[2];
        o.w = acc[z][3] + bb[3];
        *(float4*)(emis + (size_t)(b * Tn + t0 + 8 * rg + z) * Ln + 4 * cg) = o;
    }
}

// ---------------------------------------------------------------------------
// Kernel 2: per-batch CRF. grid 64 x 512. (R7 version, kept verbatim)
// wv0 = Viterbi (SIMD0), wv1 = LSE (SIMD1), wv4/wv5 idle, wv2,3,6,7 helpers
// on SIMD2/3 (8 half-wave stripes). Scan = alternating-butterfly in-register.
// ---------------------------------------------------------------------------
#define CH 64

#define VIT_BODY(T, TRARR, SWAPFN, OE)                                       \
  {                                                                          \
    int tnx2 = ((T) + 2 < slen) ? ((T) + 2) : (slen - 1);                    \
    float e2n = es[tnx2 * Ln + (OE)];                                        \
    float vv0  = av            + TRARR[0];                                   \
    float vv1  = rorf<1>(av)   + TRARR[1];                                   \
    float vv2  = rorf<2>(av)   + TRARR[2];                                   \
    float vv3  = rorf<3>(av)   + TRARR[3];                                   \
    float vv4  = rorf<4>(av)   + TRARR[4];                                   \
    float vv5  = rorf<5>(av)   + TRARR[5];                                   \
    float vv6  = rorf<6>(av)   + TRARR[6];                                   \
    float vv7  = rorf<7>(av)   + TRARR[7];                                   \
    float vv8  = rorf<8>(av)   + TRARR[8];                                   \
    float vv9  = rorf<9>(av)   + TRARR[9];                                   \
    float vv10 = rorf<10>(av)  + TRARR[10];                                  \
    float vv11 = rorf<11>(av)  + TRARR[11];                                  \
    float vv12 = rorf<12>(av)  + TRARR[12];                                  \
    float vv13 = rorf<13>(av)  + TRARR[13];                                  \
    float vv14 = rorf<14>(av)  + TRARR[14];                                  \
    float vv15 = rorf<15>(av)  + TRARR[15];                                  \
    float g0 = MAX3(vv0,  vv1,  vv2);                                        \
    float g1 = MAX3(vv3,  vv4,  vv5);                                        \
    float g2 = MAX3(vv6,  vv7,  vv8);                                        \
    float g3 = MAX3(vv9,  vv10, vv11);                                       \
    float g4 = MAX3(vv12, vv13, vv14);                                       \
    float h0 = MAX3(g0, g1, g2);                                             \
    float h1 = MAX3(g3, g4, vv15);                                           \
    float p = fmaxf(h0, h1);                                                 \
    float xx, yy; SWAPFN(p, xx, yy);                                         \
    float cmb = fmaxf(xx, yy) + emit;                                        \
    al[(T) * Ln + (OE)] = cmb;                                               \
    av = cmb;                                                                \
    emit = emitn; emitn = e2n;                                               \
  }

#define LSE_BODY(T, EARR, SWAPFN, OE, DORENORM)                              \
  {                                                                          \
    int tnx2 = ((T) + 2 < slen) ? ((T) + 2) : (slen - 1);                    \
    float rawn = es[tnx2 * Ln + (OE)];                                       \
    float een = exp2f(rawnext * LOG2E);                                      \
    float s0 = a           * EARR[0];                                        \
    float s1 = rorf<1>(a)  * EARR[1];                                        \
    float s2 = rorf<2>(a)  * EARR[2];                                        \
    float s3 = rorf<3>(a)  * EARR[3];                                        \
    s0 = fmaf(rorf<4>(a),  EARR[4],  s0);                                    \
    s1 = fmaf(rorf<5>(a),  EARR[5],  s1);                                    \
    s2 = fmaf(rorf<6>(a),  EARR[6],  s2);                                    \
    s3 = fmaf(rorf<7>(a),  EARR[7],  s3);                                    \
    s0 = fmaf(rorf<8>(a),  EARR[8],  s0);                                    \
    s1 = fmaf(rorf<9>(a),  EARR[9],  s1);                                    \
    s2 = fmaf(rorf<10>(a), EARR[10], s2);                                    \
    s3 = fmaf(rorf<11>(a), EARR[11], s3);                                    \
    s0 = fmaf(rorf<12>(a), EARR[12], s0);                                    \
    s1 = fmaf(rorf<13>(a), EARR[13], s1);                                    \
    s2 = fmaf(rorf<14>(a), EARR[14], s2);                                    \
    s3 = fmaf(rorf<15>(a), EARR[15], s3);                                    \
    float pp = (s0 + s1) + (s2 + s3);                                        \
    float xx, yy; SWAPFN(pp, xx, yy);                                        \
    float s = (xx + yy) * eemit;                                             \
    if ((DORENORM) && (((T) & 3) == 0)) {                                    \
        unsigned sb = (unsigned)__builtin_amdgcn_readfirstlane(__float_as_int(s)); \
        int e = (int)((sb >> 23) & 0xFFu) - 127;                             \
        Eacc += e;                                                           \
        a = ldexpf(s, -e);                                                   \
    } else {                                                                 \
        a = s;                                                               \
    }                                                                        \
    eemit = een; rawnext = rawn;                                             \
  }

#define BP_LOOP(PB, PE, STRIDE)                                              \
    for (int t = (PB); t < (PE); t += (STRIDE)) {                            \
        const float* ar = al + (t - 1) * Ln;                                 \
        float vv[32];                                                        \
        _Pragma("unroll")                                                    \
        for (int i = 0; i < 32; i += 4) {                                    \
            float4 a4 = *(const float4*)(ar + i);                            \
            vv[i]     = a4.x + trH[i];                                       \
            vv[i + 1] = a4.y + trH[i + 1];                                   \
            vv[i + 2] = a4.z + trH[i + 2];                                   \
            vv[i + 3] = a4.w + trH[i + 3];                                   \
        }                                                                    \
        float mv[16]; int mi[16];                                            \
        _Pragma("unroll")                                                    \
        for (int i = 0; i < 16; i++) {                                       \
            bool g = vv[2*i+1] > vv[2*i];                                    \
            mv[i] = g ? vv[2*i+1] : vv[2*i];                                 \
            mi[i] = g ? (2*i+1) : (2*i);                                     \
        }                                                                    \
        _Pragma("unroll")                                                    \
        for (int i = 0; i < 8; i++) {                                        \
            bool g = mv[2*i+1] > mv[2*i];                                    \
            mv[i] = g ? mv[2*i+1] : mv[2*i];                                 \
            mi[i] = g ? mi[2*i+1] : mi[2*i];                                 \
        }                                                                    \
        _Pragma("unroll")                                                    \
        for (int i = 0; i < 4; i++) {                                        \
            bool g = mv[2*i+1] > mv[2*i];                                    \
            mv[i] = g ? mv[2*i+1] : mv[2*i];                                 \
            mi[i] = g ? mi[2*i+1] : mi[2*i];                                 \
        }                                                                    \
        _Pragma("unroll")                                                    \
        for (int i = 0; i < 2; i++) {                                        \
            bool g = mv[2*i+1] > mv[2*i];                                    \
            mv[i] = g ? mv[2*i+1] : mv[2*i];                                 \
            mi[i] = g ? mi[2*i+1] : mi[2*i];                                 \
        }                                                                    \
        bp[t * Ln + j] = (uint8_t)mi[0];                                     \
    }

__global__ __launch_bounds__(512) void crf_forward(
    const float* __restrict__ emis, const float* __restrict__ trans,
    const int* __restrict__ label, const int* __restrict__ seqlen,
    float* __restrict__ out, float* __restrict__ wsf)
{
    __shared__ __align__(16) float es[Tn * Ln];   // 64 KB emissions
    __shared__ __align__(16) float al[Tn * Ln];   // 64 KB alphas
    __shared__ __align__(16) float trs[Ln * Ln];  // 4 KB transitions
    __shared__ uint8_t bp[Tn * Ln];               // 16 KB backpointers
    __shared__ uint8_t Fm[16 * 32];
    __shared__ int btag[16];
    __shared__ int s_last;
    __shared__ float credA[8], credB[8], credC[8];

    int tid = threadIdx.x;
    int b = blockIdx.x;
    int slen = seqlen[b];
    int wv = tid >> 6;
    int lane = tid & 63;
    int j = lane & 31;

    const float* eb = emis + (size_t)b * Tn * Ln;

    {
        int n4 = slen * (Ln / 4);
        for (int i4 = tid; i4 < n4; i4 += 512)
            ((float4*)es)[i4] = ((const float4*)eb)[i4];
    }
    if (tid < 256) ((float4*)trs)[tid] = ((const float4*)trans)[tid];
    {
        uint32_t* bp32 = (uint32_t*)bp;
        for (int w = tid; w < Tn * Ln / 4; w += 512)
            bp32[w] = 0x03020100u + 0x04040404u * (uint32_t)(w & 7);
    }

    // ---- runtime probe of DPP rotation direction (once; R4-verified) ----
    int rq[16];
    {
        float qf = (float)(lane & 15);
        rq[0]  = lane & 15;
        rq[1]  = (int)rorf<1>(qf);   rq[2]  = (int)rorf<2>(qf);
        rq[3]  = (int)rorf<3>(qf);   rq[4]  = (int)rorf<4>(qf);
        rq[5]  = (int)rorf<5>(qf);   rq[6]  = (int)rorf<6>(qf);
        rq[7]  = (int)rorf<7>(qf);   rq[8]  = (int)rorf<8>(qf);
        rq[9]  = (int)rorf<9>(qf);   rq[10] = (int)rorf<10>(qf);
        rq[11] = (int)rorf<11>(qf);  rq[12] = (int)rorf<12>(qf);
        rq[13] = (int)rorf<13>(qf);  rq[14] = (int)rorf<14>(qf);
        rq[15] = (int)rorf<15>(qf);
    }
    int q4  = lane & 15;
    int sb4 = (lane & 16) ? 16 : 0;   // bit4 source-block offset
    int sb5 = (lane & 32) ? 16 : 0;   // bit5 source-block offset
    int o4  = q4 + sb4;               // output col for A(odd) steps
    int o5  = q4 + sb5;               // output col for B(even) steps / init

    __syncthreads();

    float av = 0.f, emit = 0.f, emitn = 0.f;          // viterbi
    float a = 0.f, eemit = 0.f, rawnext = 0.f;        // LSE
    int   Eacc = 0;
    float trA[16], trB[16];
    float e2A[16], e2B[16];
    float trH[32];                                     // helpers

    int i1 = (1 < slen) ? 1 : (slen - 1);
    int i2 = (2 < slen) ? 2 : (slen - 1);

    bool isHelper = (wv == 2) || (wv == 3) || (wv == 6) || (wv == 7);
    int hw = (wv >= 6) ? (wv - 4) : (wv - 2);          // helper index 0..3
    int stripe = hw * 2 + (lane >> 5);                 // 0..7

    if (wv == 0) {
        #pragma unroll
        for (int k = 0; k < 16; k++) {
            trA[k] = trs[(rq[k] + sb5) * Ln + o4];
            trB[k] = trs[(rq[k] + sb4) * Ln + o5];
        }
        av = es[o5];                  // alpha0, bit5 layout (step-1 input)
        al[o5] = av;                  // dup-identical writes
        emit  = es[i1 * Ln + o4];     // for t=1 (A)
        emitn = es[i2 * Ln + o5];     // for t=2 (B)
    } else if (wv == 1) {
        #pragma unroll
        for (int k = 0; k < 16; k++) {
            e2A[k] = exp2f(trs[(rq[k] + sb5) * Ln + o4] * LOG2E);
            e2B[k] = exp2f(trs[(rq[k] + sb4) * Ln + o5] * LOG2E);
        }
        a = exp2f(es[o5] * LOG2E);
        eemit   = exp2f(es[i1 * Ln + o4] * LOG2E);    // for t=1 (A)
        rawnext = es[i2 * Ln + o5];                   // for t=2 (B)
    } else if (isHelper) {
        #pragma unroll
        for (int i = 0; i < 32; i++) trH[i] = trs[i * Ln + j];
    }

    for (int c = 0; c < Tn / CH; c++) {
        int tb = (c == 0) ? 1 : c * CH;
        int te = (c + 1) * CH; if (te > slen) te = slen;

        if (wv == 0) {
            int t = tb;
            if ((t & 1) && t < te) { VIT_BODY(t, trA, swap32p, o4); t++; }
            for (; t + 1 < te; t += 2) {
                VIT_BODY(t,     trB, swap16p, o5);
                VIT_BODY(t + 1, trA, swap32p, o4);
            }
            if (t < te) { VIT_BODY(t, trB, swap16p, o5); }
        } else if (wv == 1) {
            int t = tb;
            if ((t & 1) && t < te) { LSE_BODY(t, e2A, swap32p, o4, 0); t++; }
            for (; t + 1 < te; t += 2) {
                LSE_BODY(t,     e2B, swap16p, o5, 1);
                LSE_BODY(t + 1, e2A, swap32p, o4, 0);
            }
            if (t < te) { LSE_BODY(t, e2B, swap16p, o5, 1); }
        } else if (!isHelper) {
            // wv4 / wv5: idle (SIMD0/1 kept free for the scan waves)
        } else if (c == 0) {
            if (wv == 2) {
                const int* lb = label + (size_t)b * Tn;
                float acc = 0.f;
                for (int t = lane; t < Tn; t += 64) {
                    if (t < slen) {
                        int lc = lb[t];
                        acc += es[t * Ln + lc];
                        if (t >= 1) acc += trs[lb[t - 1] * Ln + lc];
                    }
                }
                #pragma unroll
                for (int off = 32; off >= 1; off >>= 1) acc += __shfl_xor(acc, off);
                if (lane == 0) wsf[SCORE_OFF + b] = acc;
            }
        } else {
            // ---------- bp recompute for chunk c-1 (8 stripes) ----------
            int pb = ((c - 1) == 0) ? 1 : (c - 1) * CH;
            int pe = c * CH; if (pe > slen) pe = slen;
            BP_LOOP(pb + stripe, pe, 8)
        }
        __syncthreads();
    }

    // tail
    if (wv == 0) {
        // layout of final av depends on parity of last executed step
        int oT = ((slen - 1) & 1) ? o4 : o5;
        float mm = av; int ai = oT;
        #pragma unroll
        for (int off = 32; off >= 1; off >>= 1) {
            float om = __shfl_xor(mm, off);
            int   oi = __shfl_xor(ai, off);
            if (om > mm || (om == mm && oi < ai)) { mm = om; ai = oi; }
        }
        if (lane == 0) s_last = ai;
    } else if (wv == 1) {
        // 64-lane sum counts each state twice -> subtract 1 from log2
        float ss = a;
        #pragma unroll
        for (int off = 32; off >= 1; off >>= 1) ss += __shfl_xor(ss, off);
        if (lane == 0)
            wsf[LOGNORM_OFF + b] = (log2f(ss) - 1.0f + (float)Eacc) * LN2f;
    } else if (isHelper) {
        int cc = Tn / CH - 1;
        int pb = cc * CH;
        int pe = Tn; if (pe > slen) pe = slen;
        BP_LOOP(pb + stripe, pe, 8)
    }
    __syncthreads();

    // ---------------- segmented parallel backtrace ----------------
    int sseg = tid >> 5, ent = tid & 31;
    {
        int y = ent;
        for (int p = 32 * sseg + 31; p >= 32 * sseg; p--) y = bp[p * Ln + y];
        Fm[sseg * 32 + ent] = (uint8_t)y;
    }
    __syncthreads();
    if (tid == 0) {
        int y = s_last;
        btag[15] = y;
        for (int ss = 15; ss >= 1; ss--) { y = Fm[ss * 32 + y]; btag[ss - 1] = y; }
    }
    __syncthreads();
    int q = tid;
    int y = btag[sseg];
    for (int p = 32 * sseg + 31; p >= q + 1; p--) y = bp[p * Ln + y];
    out[1 + (size_t)b * Tn + q] = (float)y;

    int lbl = label[(size_t)b * Tn + q];
    float tpf = (lbl > 0 && y == lbl) ? 1.f : 0.f;
    float tnf = (lbl > 0 && y != lbl) ? 1.f : 0.f;
    float fpf = (q < slen && lbl == 0 && y > 0) ? 1.f : 0.f;
    #pragma unroll
    for (int off = 32; off >= 1; off >>= 1) {
        tpf += __shfl_xor(tpf, off);
        tnf += __shfl_xor(tnf, off);
        fpf += __shfl_xor(fpf, off);
    }
    if (lane == 0) { credA[wv] = tpf; credB[wv] = tnf; credC[wv] = fpf; }
    __syncthreads();
    if (tid == 0) {
        float aa = 0.f, bb2 = 0.f, cc2 = 0.f;
        #pragma unroll
        for (int w = 0; w < 8; w++) { aa += credA[w]; bb2 += credB[w]; cc2 += credC[w]; }
        wsf[CNT_OFF + b] = aa;
        wsf[CNT_OFF + Bn + b] = bb2;
        wsf[CNT_OFF + 2 * Bn + b] = cc2;
    }
}

// ---------------------------------------------------------------------------
// Kernel 3: final scalar reductions
// ---------------------------------------------------------------------------
__global__ __launch_bounds__(64) void crf_final(const float* __restrict__ wsf,
                                                float* __restrict__ out)
{
    int lane = threadIdx.x;
    float nll = wsf[LOGNORM_OFF + lane] - wsf[SCORE_OFF + lane];
    float tp = wsf[CNT_OFF + lane];
    float tn = wsf[CNT_OFF + Bn + lane];
    float fp = wsf[CNT_OFF + 2 * Bn + lane];
    #pragma unroll
    for (int off = 32; off >= 1; off >>= 1) {
        nll += __shfl_xor(nll, off);
        tp  += __shfl_xor(tp, off);
        tn  += __shfl_xor(tn, off);
        fp  += __shfl_xor(fp, off);
    }
    if (lane == 0) {
        out[0] = nll * (1.f / 64.f);
        out[1 + Bn * Tn + 0] = tp;
        out[1 + Bn * Tn + 1] = tn;
        out[1 + Bn * Tn + 2] = fp;
    }
}

extern "C" void kernel_launch(void* const* d_in, const int* in_sizes, int n_in,
                              void* d_out, int out_size, void* d_ws, size_t ws_size,
                              hipStream_t stream) {
    const float* x     = (const float*)d_in[0];
    const float* W     = (const float*)d_in[1];
    const float* bias  = (const float*)d_in[2];
    const float* trans = (const float*)d_in[3];
    const int* label   = (const int*)d_in[4];
    const int* seqlen  = (const int*)d_in[5];
    float* out = (float*)d_out;
    float* wsf = (float*)d_ws;

    gemm_emis<<<dim3(Bn * (Tn / BM)), dim3(128), 0, stream>>>(x, W, bias, seqlen, wsf + EMIS_OFF);
    crf_forward<<<dim3(Bn), dim3(512), 0, stream>>>(wsf + EMIS_OFF, trans, label, seqlen, out, wsf);
    crf_final<<<dim3(1), dim3(64), 0, stream>>>(wsf, out);
}

// Round 9
// 265.609 us; speedup vs baseline: 1.2749x; 1.2749x over previous
//
#include <hip/hip_runtime.h>
#include <stdint.h>
#include <math.h>

#define Bn 64
#define Tn 512
#define Dn 1024
#define Ln 32
#define LOG2E 1.4426950408889634f
#define LN2f  0.6931471805599453f

// workspace float offsets
#define EMIS_OFF 0
#define LOGNORM_OFF (Bn * Tn * Ln)
#define SCORE_OFF (LOGNORM_OFF + Bn)
#define CNT_OFF (SCORE_OFF + Bn)

// max3 helper: compiler fuses fmaxf(fmaxf(a,b),c) -> v_max3_f32
#define MAX3(a,b,c) fmaxf(fmaxf((a),(b)),(c))

// DPP row rotate (16-lane row), K = compile-time rotate amount.
// Used for the one-time direction probe only (hot loops use fused DPP asm
// with the IDENTICAL ctrl encoding 0x120|K == row_ror:K).
template<int K>
__device__ __forceinline__ float rorf(float v) {
    return __int_as_float(__builtin_amdgcn_update_dpp(
        0, __float_as_int(v), 0x120 | K, 0xF, 0xF, true));
}

// Opaque register copy: compiler cannot prove r == v, so the two swap
// operands land in distinct physical registers (R3 bugfix, R4-verified).
__device__ __forceinline__ float opaque_copy(float v) {
    float r;
    asm("v_mov_b32 %0, %1" : "=v"(r) : "v"(v));
    return r;
}

// cross-lane swaps; after the op {x,y} hold {own, other} in some order on
// every lane, so a commutative combine needs no polarity select.
__device__ __forceinline__ void swap32p(float p, float& x, float& y) {
    x = p;
    y = opaque_copy(p);
    asm("v_permlane32_swap_b32 %0, %1" : "+v"(x), "+v"(y));
}
__device__ __forceinline__ void swap16p(float p, float& x, float& y) {
    x = p;
    y = opaque_copy(p);
    asm("v_permlane16_swap_b32 %0, %1" : "+v"(x), "+v"(y));
}

// ---------------------------------------------------------------------------
// Kernel 1: emissions = x @ W + bias. 256 blocks x 256 threads.
// R9: reverted to the R6-verified version (R7 2x4-tile and R8 8x4-tile both
// regressed: R8 showed 1.84M LDS bank conflicts + VGPR=64 prefetch serialize).
// ---------------------------------------------------------------------------
#define BM 128
#define KB 32
#define XSS 132

__global__ __launch_bounds__(256) void gemm_emis(
    const float* __restrict__ x, const float* __restrict__ Wm,
    const float* __restrict__ bias, const int* __restrict__ seqlen,
    float* __restrict__ emis)
{
    int b  = blockIdx.x >> 2;
    int t0 = (blockIdx.x & 3) * BM;
    if (t0 >= seqlen[b]) return;

    __shared__ __align__(16) float xs[KB * XSS];   // transposed: xs[k][row]
    __shared__ __align__(16) float wsh[KB * Ln];   // wsh[k][col]

    int tid = threadIdx.x;
    int cg = tid & 7;       // cols 4cg..4cg+3
    int rg = tid >> 3;      // rows 4rg..4rg+3 (0..31)

    const float* xrow = x + (size_t)(b * Tn + t0) * Dn;

    float acc[4][4];
    #pragma unroll
    for (int z = 0; z < 4; z++)
        #pragma unroll
        for (int c = 0; c < 4; c++) acc[z][c] = 0.f;

    // prologue: prefetch chunk 0 into registers
    float4 xr[4]; float4 wr;
    #pragma unroll
    for (int u = 0; u < 4; u++) {
        int f = tid + 256 * u;
        xr[u] = *(const float4*)(xrow + (size_t)(f >> 3) * Dn + (f & 7) * 4);
    }
    wr = *(const float4*)(Wm + tid * 4);

    for (int k0 = 0; k0 < Dn; k0 += KB) {
        __syncthreads();
        #pragma unroll
        for (int u = 0; u < 4; u++) {
            int f = tid + 256 * u;
            int lrow = f >> 3, kk = f & 7;
            xs[(4 * kk + 0) * XSS + lrow] = xr[u].x;
            xs[(4 * kk + 1) * XSS + lrow] = xr[u].y;
            xs[(4 * kk + 2) * XSS + lrow] = xr[u].z;
            xs[(4 * kk + 3) * XSS + lrow] = xr[u].w;
        }
        *(float4*)(wsh + tid * 4) = wr;
        __syncthreads();

        int kn = k0 + KB;
        if (kn < Dn) {
            #pragma unroll
            for (int u = 0; u < 4; u++) {
                int f = tid + 256 * u;
                xr[u] = *(const float4*)(xrow + (size_t)(f >> 3) * Dn + kn + (f & 7) * 4);
            }
            wr = *(const float4*)(Wm + (size_t)kn * Ln + tid * 4);
        }

        #pragma unroll 8
        for (int k = 0; k < KB; k++) {
            float4 a = *(const float4*)(xs + k * XSS + 4 * rg);
            float4 w = *(const float4*)(wsh + k * Ln + 4 * cg);
            float av[4] = {a.x, a.y, a.z, a.w};
            float wv[4] = {w.x, w.y, w.z, w.w};
            #pragma unroll
            for (int z = 0; z < 4; z++)
                #pragma unroll
                for (int c = 0; c < 4; c++)
                    acc[z][c] = fmaf(av[z], wv[c], acc[z][c]);
        }
    }

    float4 bv = *(const float4*)(bias + 4 * cg);
    float bb[4] = {bv.x, bv.y, bv.z, bv.w};
    #pragma unroll
    for (int z = 0; z < 4; z++) {
        float4 o;
        o.x = acc[z][0] + bb[0];
        o.y = acc[z][1] + bb[1];
        o.z = acc[z][2] + bb[2];
        o.w = acc[z][3] + bb[3];
        *(float4*)(emis + (size_t)(b * Tn + t0 + 4 * rg + z) * Ln + 4 * cg) = o;
    }
}

// ---------------------------------------------------------------------------
// Kernel 2: per-batch CRF. grid 64 x 512. R6 wave map (wv0 VIT, wv1 LSE,
// wv2-7 helpers/12 stripes). R9 change: the DPP gather is FUSED into the
// arithmetic via v_add_f32_dpp / v_mul_f32_dpp / v_fmac_f32_dpp inline asm
// (one instr per source instead of mov_dpp + op). s_nop 1 guards the
// VALU-write -> DPP-read hazard on the recurrence register; outputs are
// early-clobber. DPP ctrl identical to the rorf probe (row_ror:K).
// ---------------------------------------------------------------------------
#define CH 64

#define DPPMODS " row_mask:0xf bank_mask:0xf bound_ctrl:0\n\t"

#define VIT_BODY(T, TRARR, SWAPFN, OE)                                       \
  {                                                                          \
    int tnx2 = ((T) + 2 < slen) ? ((T) + 2) : (slen - 1);                    \
    float e2n = es[tnx2 * Ln + (OE)];                                        \
    float vv0 = av + TRARR[0];                                               \
    float w1, w2, w3, w4, w5, w6, w7, w8, w9, w10, w11, w12, w13, w14, w15;  \
    asm("s_nop 1\n\t"                                                        \
        "v_add_f32_dpp %0, %15, %16 row_ror:1" DPPMODS                       \
        "v_add_f32_dpp %1, %15, %17 row_ror:2" DPPMODS                       \
        "v_add_f32_dpp %2, %15, %18 row_ror:3" DPPMODS                       \
        "v_add_f32_dpp %3, %15, %19 row_ror:4" DPPMODS                       \
        "v_add_f32_dpp %4, %15, %20 row_ror:5" DPPMODS                       \
        "v_add_f32_dpp %5, %15, %21 row_ror:6" DPPMODS                       \
        "v_add_f32_dpp %6, %15, %22 row_ror:7" DPPMODS                       \
        "v_add_f32_dpp %7, %15, %23 row_ror:8" DPPMODS                       \
        "v_add_f32_dpp %8, %15, %24 row_ror:9" DPPMODS                       \
        "v_add_f32_dpp %9, %15, %25 row_ror:10" DPPMODS                      \
        "v_add_f32_dpp %10, %15, %26 row_ror:11" DPPMODS                     \
        "v_add_f32_dpp %11, %15, %27 row_ror:12" DPPMODS                     \
        "v_add_f32_dpp %12, %15, %28 row_ror:13" DPPMODS                     \
        "v_add_f32_dpp %13, %15, %29 row_ror:14" DPPMODS                     \
        "v_add_f32_dpp %14, %15, %30 row_ror:15" DPPMODS                     \
        : "=&v"(w1), "=&v"(w2), "=&v"(w3), "=&v"(w4), "=&v"(w5),             \
          "=&v"(w6), "=&v"(w7), "=&v"(w8), "=&v"(w9), "=&v"(w10),            \
          "=&v"(w11), "=&v"(w12), "=&v"(w13), "=&v"(w14), "=&v"(w15)         \
        : "v"(av), "v"(TRARR[1]), "v"(TRARR[2]), "v"(TRARR[3]),              \
          "v"(TRARR[4]), "v"(TRARR[5]), "v"(TRARR[6]), "v"(TRARR[7]),        \
          "v"(TRARR[8]), "v"(TRARR[9]), "v"(TRARR[10]), "v"(TRARR[11]),      \
          "v"(TRARR[12]), "v"(TRARR[13]), "v"(TRARR[14]), "v"(TRARR[15]));   \
    float g0 = MAX3(vv0, w1,  w2);                                           \
    float g1 = MAX3(w3,  w4,  w5);                                           \
    float g2 = MAX3(w6,  w7,  w8);                                           \
    float g3 = MAX3(w9,  w10, w11);                                          \
    float g4 = MAX3(w12, w13, w14);                                          \
    float h0 = MAX3(g0, g1, g2);                                             \
    float h1 = MAX3(g3, g4, w15);                                            \
    float p = fmaxf(h0, h1);                                                 \
    float xx, yy; SWAPFN(p, xx, yy);                                         \
    float cmb = fmaxf(xx, yy) + emit;                                        \
    al[(T) * Ln + (OE)] = cmb;                                               \
    av = cmb;                                                                \
    emit = emitn; emitn = e2n;                                               \
  }

#define LSE_BODY(T, EARR, SWAPFN, OE, DORENORM)                              \
  {                                                                          \
    int tnx2 = ((T) + 2 < slen) ? ((T) + 2) : (slen - 1);                    \
    float rawn = es[tnx2 * Ln + (OE)];                                       \
    float een = exp2f(rawnext * LOG2E);                                      \
    float s0, s1, s2, s3;                                                    \
    asm("s_nop 1\n\t"                                                        \
        "v_mul_f32 %0, %4, %5\n\t"                                           \
        "v_mul_f32_dpp %1, %4, %6 row_ror:1" DPPMODS                         \
        "v_mul_f32_dpp %2, %4, %7 row_ror:2" DPPMODS                         \
        "v_mul_f32_dpp %3, %4, %8 row_ror:3" DPPMODS                         \
        "v_fmac_f32_dpp %0, %4, %9 row_ror:4" DPPMODS                        \
        "v_fmac_f32_dpp %1, %4, %10 row_ror:5" DPPMODS                       \
        "v_fmac_f32_dpp %2, %4, %11 row_ror:6" DPPMODS                       \
        "v_fmac_f32_dpp %3, %4, %12 row_ror:7" DPPMODS                       \
        "v_fmac_f32_dpp %0, %4, %13 row_ror:8" DPPMODS                       \
        "v_fmac_f32_dpp %1, %4, %14 row_ror:9" DPPMODS                       \
        "v_fmac_f32_dpp %2, %4, %15 row_ror:10" DPPMODS                      \
        "v_fmac_f32_dpp %3, %4, %16 row_ror:11" DPPMODS                      \
        "v_fmac_f32_dpp %0, %4, %17 row_ror:12" DPPMODS                      \
        "v_fmac_f32_dpp %1, %4, %18 row_ror:13" DPPMODS                      \
        "v_fmac_f32_dpp %2, %4, %19 row_ror:14" DPPMODS                      \
        "v_fmac_f32_dpp %3, %4, %20 row_ror:15" DPPMODS                      \
        : "=&v"(s0), "=&v"(s1), "=&v"(s2), "=&v"(s3)                         \
        : "v"(a), "v"(EARR[0]), "v"(EARR[1]), "v"(EARR[2]), "v"(EARR[3]),    \
          "v"(EARR[4]), "v"(EARR[5]), "v"(EARR[6]), "v"(EARR[7]),            \
          "v"(EARR[8]), "v"(EARR[9]), "v"(EARR[10]), "v"(EARR[11]),          \
          "v"(EARR[12]), "v"(EARR[13]), "v"(EARR[14]), "v"(EARR[15]));       \
    float pp = (s0 + s1) + (s2 + s3);                                        \
    float xx, yy; SWAPFN(pp, xx, yy);                                        \
    float s = (xx + yy) * eemit;                                             \
    if ((DORENORM) && (((T) & 3) == 0)) {                                    \
        unsigned sb = (unsigned)__builtin_amdgcn_readfirstlane(__float_as_int(s)); \
        int e = (int)((sb >> 23) & 0xFFu) - 127;                             \
        Eacc += e;                                                           \
        a = ldexpf(s, -e);                                                   \
    } else {                                                                 \
        a = s;                                                               \
    }                                                                        \
    eemit = een; rawnext = rawn;                                             \
  }

__global__ __launch_bounds__(512) void crf_forward(
    const float* __restrict__ emis, const float* __restrict__ trans,
    const int* __restrict__ label, const int* __restrict__ seqlen,
    float* __restrict__ out, float* __restrict__ wsf)
{
    __shared__ __align__(16) float es[Tn * Ln];   // 64 KB emissions
    __shared__ __align__(16) float al[Tn * Ln];   // 64 KB alphas
    __shared__ __align__(16) float trs[Ln * Ln];  // 4 KB transitions
    __shared__ uint8_t bp[Tn * Ln];               // 16 KB backpointers
    __shared__ uint8_t Fm[16 * 32];
    __shared__ int btag[16];
    __shared__ int s_last;
    __shared__ float credA[8], credB[8], credC[8];

    int tid = threadIdx.x;
    int b = blockIdx.x;
    int slen = seqlen[b];
    int wv = tid >> 6;
    int lane = tid & 63;
    int j = lane & 31;

    const float* eb = emis + (size_t)b * Tn * Ln;

    {
        int n4 = slen * (Ln / 4);
        for (int i4 = tid; i4 < n4; i4 += 512)
            ((float4*)es)[i4] = ((const float4*)eb)[i4];
    }
    if (tid < 256) ((float4*)trs)[tid] = ((const float4*)trans)[tid];
    {
        uint32_t* bp32 = (uint32_t*)bp;
        for (int w = tid; w < Tn * Ln / 4; w += 512)
            bp32[w] = 0x03020100u + 0x04040404u * (uint32_t)(w & 7);
    }

    // ---- runtime probe of DPP rotation direction (once; R4-verified) ----
    int rq[16];
    {
        float qf = (float)(lane & 15);
        rq[0]  = lane & 15;
        rq[1]  = (int)rorf<1>(qf);   rq[2]  = (int)rorf<2>(qf);
        rq[3]  = (int)rorf<3>(qf);   rq[4]  = (int)rorf<4>(qf);
        rq[5]  = (int)rorf<5>(qf);   rq[6]  = (int)rorf<6>(qf);
        rq[7]  = (int)rorf<7>(qf);   rq[8]  = (int)rorf<8>(qf);
        rq[9]  = (int)rorf<9>(qf);   rq[10] = (int)rorf<10>(qf);
        rq[11] = (int)rorf<11>(qf);  rq[12] = (int)rorf<12>(qf);
        rq[13] = (int)rorf<13>(qf);  rq[14] = (int)rorf<14>(qf);
        rq[15] = (int)rorf<15>(qf);
    }
    int q4  = lane & 15;
    int sb4 = (lane & 16) ? 16 : 0;   // bit4 source-block offset
    int sb5 = (lane & 32) ? 16 : 0;   // bit5 source-block offset
    int o4  = q4 + sb4;               // output col for A(odd) steps
    int o5  = q4 + sb5;               // output col for B(even) steps / init

    __syncthreads();

    float av = 0.f, emit = 0.f, emitn = 0.f;          // viterbi
    float a = 0.f, eemit = 0.f, rawnext = 0.f;        // LSE
    int   Eacc = 0;
    float trA[16], trB[16];
    float e2A[16], e2B[16];
    float trH[32];                                     // helpers

    int i1 = (1 < slen) ? 1 : (slen - 1);
    int i2 = (2 < slen) ? 2 : (slen - 1);

    if (wv == 0) {
        #pragma unroll
        for (int k = 0; k < 16; k++) {
            trA[k] = trs[(rq[k] + sb5) * Ln + o4];
            trB[k] = trs[(rq[k] + sb4) * Ln + o5];
        }
        av = es[o5];                  // alpha0, bit5 layout (step-1 input)
        al[o5] = av;                  // dup-identical writes
        emit  = es[i1 * Ln + o4];     // for t=1 (A)
        emitn = es[i2 * Ln + o5];     // for t=2 (B)
    } else if (wv == 1) {
        #pragma unroll
        for (int k = 0; k < 16; k++) {
            e2A[k] = exp2f(trs[(rq[k] + sb5) * Ln + o4] * LOG2E);
            e2B[k] = exp2f(trs[(rq[k] + sb4) * Ln + o5] * LOG2E);
        }
        a = exp2f(es[o5] * LOG2E);
        eemit   = exp2f(es[i1 * Ln + o4] * LOG2E);    // for t=1 (A)
        rawnext = es[i2 * Ln + o5];                   // for t=2 (B)
    } else {
        #pragma unroll
        for (int i = 0; i < 32; i++) trH[i] = trs[i * Ln + j];
    }

    for (int c = 0; c < Tn / CH; c++) {
        int tb = (c == 0) ? 1 : c * CH;
        int te = (c + 1) * CH; if (te > slen) te = slen;

        if (wv == 0) {
            int t = tb;
            if ((t & 1) && t < te) { VIT_BODY(t, trA, swap32p, o4); t++; }
            for (; t + 1 < te; t += 2) {
                VIT_BODY(t,     trB, swap16p, o5);
                VIT_BODY(t + 1, trA, swap32p, o4);
            }
            if (t < te) { VIT_BODY(t, trB, swap16p, o5); }
        } else if (wv == 1) {
            int t = tb;
            if ((t & 1) && t < te) { LSE_BODY(t, e2A, swap32p, o4, 0); t++; }
            for (; t + 1 < te; t += 2) {
                LSE_BODY(t,     e2B, swap16p, o5, 1);
                LSE_BODY(t + 1, e2A, swap32p, o4, 0);
            }
            if (t < te) { LSE_BODY(t, e2B, swap16p, o5, 1); }
        } else if (c == 0) {
            if (wv == 2) {
                const int* lb = label + (size_t)b * Tn;
                float acc = 0.f;
                for (int t = lane; t < Tn; t += 64) {
                    if (t < slen) {
                        int lc = lb[t];
                        acc += es[t * Ln + lc];
                        if (t >= 1) acc += trs[lb[t - 1] * Ln + lc];
                    }
                }
                #pragma unroll
                for (int off = 32; off >= 1; off >>= 1) acc += __shfl_xor(acc, off);
                if (lane == 0) wsf[SCORE_OFF + b] = acc;
            }
        } else {
            // ---------- bp recompute for chunk c-1 (12 stripes) ----------
            int stripe = (wv - 2) * 2 + (lane >> 5);
            int pb = ((c - 1) == 0) ? 1 : (c - 1) * CH;
            int pe = c * CH; if (pe > slen) pe = slen;
            for (int t = pb + stripe; t < pe; t += 12) {
                const float* ar = al + (t - 1) * Ln;
                float vv[32];
                #pragma unroll
                for (int i = 0; i < 32; i += 4) {
                    float4 a4 = *(const float4*)(ar + i);
                    vv[i]     = a4.x + trH[i];
                    vv[i + 1] = a4.y + trH[i + 1];
                    vv[i + 2] = a4.z + trH[i + 2];
                    vv[i + 3] = a4.w + trH[i + 3];
                }
                float mv[16]; int mi[16];
                #pragma unroll
                for (int i = 0; i < 16; i++) {
                    bool g = vv[2*i+1] > vv[2*i];
                    mv[i] = g ? vv[2*i+1] : vv[2*i];
                    mi[i] = g ? (2*i+1) : (2*i);
                }
                #pragma unroll
                for (int i = 0; i < 8; i++) {
                    bool g = mv[2*i+1] > mv[2*i];
                    mv[i] = g ? mv[2*i+1] : mv[2*i];
                    mi[i] = g ? mi[2*i+1] : mi[2*i];
                }
                #pragma unroll
                for (int i = 0; i < 4; i++) {
                    bool g = mv[2*i+1] > mv[2*i];
                    mv[i] = g ? mv[2*i+1] : mv[2*i];
                    mi[i] = g ? mi[2*i+1] : mi[2*i];
                }
                #pragma unroll
                for (int i = 0; i < 2; i++) {
                    bool g = mv[2*i+1] > mv[2*i];
                    mv[i] = g ? mv[2*i+1] : mv[2*i];
                    mi[i] = g ? mi[2*i+1] : mi[2*i];
                }
                bp[t * Ln + j] = (uint8_t)mi[0];
            }
        }
        __syncthreads();
    }

    // tail
    if (wv == 0) {
        // layout of final av depends on parity of last executed step
        int oT = ((slen - 1) & 1) ? o4 : o5;
        float mm = av; int ai = oT;
        #pragma unroll
        for (int off = 32; off >= 1; off >>= 1) {
            float om = __shfl_xor(mm, off);
            int   oi = __shfl_xor(ai, off);
            if (om > mm || (om == mm && oi < ai)) { mm = om; ai = oi; }
        }
        if (lane == 0) s_last = ai;
    } else if (wv == 1) {
        // 64-lane sum counts each state twice -> subtract 1 from log2
        float ss = a;
        #pragma unroll
        for (int off = 32; off >= 1; off >>= 1) ss += __shfl_xor(ss, off);
        if (lane == 0)
            wsf[LOGNORM_OFF + b] = (log2f(ss) - 1.0f + (float)Eacc) * LN2f;
    } else {
        int stripe = (wv - 2) * 2 + (lane >> 5);
        int cc = Tn / CH - 1;
        int pb = cc * CH;
        int pe = Tn; if (pe > slen) pe = slen;
        for (int t = pb + stripe; t < pe; t += 12) {
            const float* ar = al + (t - 1) * Ln;
            float vv[32];
            #pragma unroll
            for (int i = 0; i < 32; i += 4) {
                float4 a4 = *(const float4*)(ar + i);
                vv[i]     = a4.x + trH[i];
                vv[i + 1] = a4.y + trH[i + 1];
                vv[i + 2] = a4.z + trH[i + 2];
                vv[i + 3] = a4.w + trH[i + 3];
            }
            float mv[16]; int mi[16];
            #pragma unroll
            for (int i = 0; i < 16; i++) {
                bool g = vv[2*i+1] > vv[2*i];
                mv[i] = g ? vv[2*i+1] : vv[2*i];
                mi[i] = g ? (2*i+1) : (2*i);
            }
            #pragma unroll
            for (int i = 0; i < 8; i++) {
                bool g = mv[2*i+1] > mv[2*i];
                mv[i] = g ? mv[2*i+1] : mv[2*i];
                mi[i] = g ? mi[2*i+1] : mi[2*i];
            }
            #pragma unroll
            for (int i = 0; i < 4; i++) {
                bool g = mv[2*i+1] > mv[2*i];
                mv[i] = g ? mv[2*i+1] : mv[2*i];
                mi[i] = g ? mi[2*i+1] : mi[2*i];
            }
            #pragma unroll
            for (int i = 0; i < 2; i++) {
                bool g = mv[2*i+1] > mv[2*i];
                mv[i] = g ? mv[2*i+1] : mv[2*i];
                mi[i] = g ? mi[2*i+1] : mi[2*i];
            }
            bp[t * Ln + j] = (uint8_t)mi[0];
        }
    }
    __syncthreads();

    // ---------------- segmented parallel backtrace ----------------
    int sseg = tid >> 5, ent = tid & 31;
    {
        int y = ent;
        for (int p = 32 * sseg + 31; p >= 32 * sseg; p--) y = bp[p * Ln + y];
        Fm[sseg * 32 + ent] = (uint8_t)y;
    }
    __syncthreads();
    if (tid == 0) {
        int y = s_last;
        btag[15] = y;
        for (int ss = 15; ss >= 1; ss--) { y = Fm[ss * 32 + y]; btag[ss - 1] = y; }
    }
    __syncthreads();
    int q = tid;
    int y = btag[sseg];
    for (int p = 32 * sseg + 31; p >= q + 1; p--) y = bp[p * Ln + y];
    out[1 + (size_t)b * Tn + q] = (float)y;

    int lbl = label[(size_t)b * Tn + q];
    float tpf = (lbl > 0 && y == lbl) ? 1.f : 0.f;
    float tnf = (lbl > 0 && y != lbl) ? 1.f : 0.f;
    float fpf = (q < slen && lbl == 0 && y > 0) ? 1.f : 0.f;
    #pragma unroll
    for (int off = 32; off >= 1; off >>= 1) {
        tpf += __shfl_xor(tpf, off);
        tnf += __shfl_xor(tnf, off);
        fpf += __shfl_xor(fpf, off);
    }
    if (lane == 0) { credA[wv] = tpf; credB[wv] = tnf; credC[wv] = fpf; }
    __syncthreads();
    if (tid == 0) {
        float aa = 0.f, bb2 = 0.f, cc2 = 0.f;
        #pragma unroll
        for (int w = 0; w < 8; w++) { aa += credA[w]; bb2 += credB[w]; cc2 += credC[w]; }
        wsf[CNT_OFF + b] = aa;
        wsf[CNT_OFF + Bn + b] = bb2;
        wsf[CNT_OFF + 2 * Bn + b] = cc2;
    }
}

// ---------------------------------------------------------------------------
// Kernel 3: final scalar reductions
// ---------------------------------------------------------------------------
__global__ __launch_bounds__(64) void crf_final(const float* __restrict__ wsf,
                                                float* __restrict__ out)
{
    int lane = threadIdx.x;
    float nll = wsf[LOGNORM_OFF + lane] - wsf[SCORE_OFF + lane];
    float tp = wsf[CNT_OFF + lane];
    float tn = wsf[CNT_OFF + Bn + lane];
    float fp = wsf[CNT_OFF + 2 * Bn + lane];
    #pragma unroll
    for (int off = 32; off >= 1; off >>= 1) {
        nll += __shfl_xor(nll, off);
        tp  += __shfl_xor(tp, off);
        tn  += __shfl_xor(tn, off);
        fp  += __shfl_xor(fp, off);
    }
    if (lane == 0) {
        out[0] = nll * (1.f / 64.f);
        out[1 + Bn * Tn + 0] = tp;
        out[1 + Bn * Tn + 1] = tn;
        out[1 + Bn * Tn + 2] = fp;
    }
}

extern "C" void kernel_launch(void* const* d_in, const int* in_sizes, int n_in,
                              void* d_out, int out_size, void* d_ws, size_t ws_size,
                              hipStream_t stream) {
    const float* x     = (const float*)d_in[0];
    const float* W     = (const float*)d_in[1];
    const float* bias  = (const float*)d_in[2];
    const float* trans = (const float*)d_in[3];
    const int* label   = (const int*)d_in[4];
    const int* seqlen  = (const int*)d_in[5];
    float* out = (float*)d_out;
    float* wsf = (float*)d_ws;

    gemm_emis<<<dim3(Bn * (Tn / BM)), dim3(256), 0, stream>>>(x, W, bias, seqlen, wsf + EMIS_OFF);
    crf_forward<<<dim3(Bn), dim3(512), 0, stream>>>(wsf + EMIS_OFF, trans, label, seqlen, out, wsf);
    crf_final<<<dim3(1), dim3(64), 0, stream>>>(wsf, out);
}